// Round 4
// baseline (459.613 us; speedup 1.0000x reference)
//
#include <hip/hip_runtime.h>

// AVWGCN: out[b,n,o] = sum_k sum_i xg_k[b,n,i] * w[k,i,o] + bias[o]
//   xg0 = x, xg1 = S@x, xg2 = 2*S@(S@x) - x   (S = softmax(relu(adj@emb), rows))
// Algebra: never form T2; fold "2*" and "-x" into Wcat = [w0-w2 | w1 | 2*w2].
// GEMM: 256x256, BK=64, 8 waves, 128 KiB LDS dbuf, chunk-XOR swizzle (0 conflicts,
// round-2 PMC). ROTATED single-barrier schedule: region p reads the operands for
// region p+1's MFMA (balanced 8/4 reads per region, no same-region read->MFMA
// dependency), stage schedule identical to round-3, vmcnt(4) at R3/R7 only,
// lgkmcnt(0) before every barrier (forces read-completion for stage safety; free
// since the MFMA burst covers the wave's own reads).

typedef __bf16 bf16;
typedef __bf16 bf16x8 __attribute__((ext_vector_type(8)));
typedef float f32x4 __attribute__((ext_vector_type(4)));

__device__ __forceinline__ void async_lds16(const void* g, void* l) {
  __builtin_amdgcn_global_load_lds((const __attribute__((address_space(1))) void*)g,
                                   (__attribute__((address_space(3))) void*)l, 16, 0, 0);
}

#define FENCE() asm volatile("" ::: "memory")
#define BAR()                          \
  do {                                 \
    FENCE();                           \
    __builtin_amdgcn_s_barrier();      \
    FENCE();                           \
  } while (0)
#define WAIT_VM(n) asm volatile("s_waitcnt vmcnt(" #n ")" ::: "memory")
#define LGKM0() asm volatile("s_waitcnt lgkmcnt(0)" ::: "memory")

// ---- Wcat[o][kk] bf16, kk in [0,192): [w0-w2 | w1 | 2*w2] transposed to o-rows ----
__global__ __launch_bounds__(256) void build_wcat_k(const float* __restrict__ w, bf16* __restrict__ Wc) {
  int idx = blockIdx.x * 256 + threadIdx.x;
  if (idx >= 64 * 192) return;
  int o = idx / 192, kk = idx - o * 192;
  int k = kk >> 6, i = kk & 63;
  float v;
  if (k == 0)      v = w[i * 64 + o] - w[2 * 4096 + i * 64 + o];
  else if (k == 1) v = w[4096 + i * 64 + o];
  else             v = 2.f * w[2 * 4096 + i * 64 + o];
  Wc[idx] = (bf16)v;
}

// ---- S[n][m] = softmax(relu(adj@emb)) rows, stored bf16. 8 rows per block. ----
__global__ __launch_bounds__(256) void supports_k(const float* __restrict__ adj,
                                                  const float* __restrict__ emb,
                                                  bf16* __restrict__ S) {
  __shared__ float sadj[8][16];
  __shared__ float sred[4];
  const int tid = threadIdx.x;
  const int n0 = blockIdx.x * 8;
  if (tid < 128) sadj[tid >> 4][tid & 15] = adj[n0 * 16 + tid];
  __syncthreads();
  for (int r = 0; r < 8; ++r) {
    float vals[16];
    float mx = 0.f;  // relu => max >= 0
    #pragma unroll
    for (int it = 0; it < 16; ++it) {
      const int j = it * 256 + tid;
      float v = 0.f;
      #pragma unroll
      for (int e = 0; e < 16; ++e) v = fmaf(sadj[r][e], emb[e * 4096 + j], v);
      v = fmaxf(v, 0.f);
      vals[it] = v;
      mx = fmaxf(mx, v);
    }
    #pragma unroll
    for (int off = 32; off > 0; off >>= 1) mx = fmaxf(mx, __shfl_xor(mx, off, 64));
    if ((tid & 63) == 0) sred[tid >> 6] = mx;
    __syncthreads();
    mx = fmaxf(fmaxf(sred[0], sred[1]), fmaxf(sred[2], sred[3]));
    float sum = 0.f;
    #pragma unroll
    for (int it = 0; it < 16; ++it) {
      float ev = __expf(vals[it] - mx);
      vals[it] = ev;
      sum += ev;
    }
    #pragma unroll
    for (int off = 32; off > 0; off >>= 1) sum += __shfl_xor(sum, off, 64);
    __syncthreads();  // all reads of sred (max) done before reuse
    if ((tid & 63) == 0) sred[tid >> 6] = sum;
    __syncthreads();
    const float inv = 1.f / (sred[0] + sred[1] + sred[2] + sred[3]);
    bf16* Srow = S + (n0 + r) * 4096;
    #pragma unroll
    for (int it = 0; it < 16; ++it) Srow[it * 256 + tid] = (bf16)(vals[it] * inv);
    __syncthreads();  // sred reused next r
  }
}

// ---- Xt[b*64+c][m] = bf16(x[b][m][c])  (64x64 fp32 tile via LDS) ----
__global__ __launch_bounds__(256) void xpose_x_k(const float* __restrict__ x, bf16* __restrict__ Xt) {
  __shared__ float tile[64][65];
  const int tid = threadIdx.x;
  const int mt = blockIdx.x, b = blockIdx.y;
  const float* src = x + (b * 4096 + mt * 64) * 64;
  #pragma unroll
  for (int it = 0; it < 16; ++it) {
    const int idx = it * 256 + tid;
    tile[idx >> 6][idx & 63] = src[idx];  // idx = m_local*64 + c, coalesced
  }
  __syncthreads();
  #pragma unroll
  for (int it = 0; it < 16; ++it) {
    const int idx = it * 256 + tid;
    const int rr = idx >> 6, cc = idx & 63;  // rr = c (out row), cc = m_local (out col)
    Xt[(b * 64 + rr) * 4096 + mt * 64 + cc] = (bf16)tile[cc][rr];
  }
}

// ---- bf16 4096x4096 transpose: outT[j][i] = in[i][j]  (fallback if ws too small) ----
__global__ __launch_bounds__(256) void transpose_bf16_k(const bf16* __restrict__ in, bf16* __restrict__ outT) {
  __shared__ bf16 tile[64][65];
  const int tid = threadIdx.x;
  const int ti = blockIdx.x & 63, tj = blockIdx.x >> 6;
  #pragma unroll
  for (int it = 0; it < 16; ++it) {
    const int idx = it * 256 + tid;
    tile[idx >> 6][idx & 63] = in[(ti * 64 + (idx >> 6)) * 4096 + tj * 64 + (idx & 63)];
  }
  __syncthreads();
  #pragma unroll
  for (int it = 0; it < 16; ++it) {
    const int idx = it * 256 + tid;
    const int rr = idx >> 6, cc = idx & 63;
    outT[(tj * 64 + rr) * 4096 + ti * 64 + cc] = tile[cc][rr];
  }
}

// ---- C[n][bc] = A[n][:] . Bt[bc][:]  (4096^3, both operands K-contig row-major) ----
// Regions R1..R8 over 2 K-tiles (t=2i buf0, t+1 buf1), ONE barrier each.
// Region p: { ds_reads for region p+1's MFMA (8 or 4) | stage 1 half | [R3/R7:
// WAIT_VM(4)] | 16 MFMA on regs read in region p-1 | lgkmcnt(0) | BAR }.
// Stage order (same as round-3): R1 t+1.Aks1 | R2 t+2.Bks0 | R3 t+2.Aks0 |
// R4 t+2.Bks1 | R5 t+2.Aks1 | R6 t+3.Bks0 | R7 t+3.Aks0 | R8 t+3.Bks1.
// WAIT_VM(4)@R3: t+1 complete (after its last stage X1, only X2,X3 = 4 loads
// outstanding); buf1 reads start in R4 (after BAR R3). Same for R7 / t+2 / R8.
// Stage-safety: every overwritten half's last read completes >=1 barrier before
// the stage (lgkmcnt(0) at each region end forces it).
// Chunk swizzle: phys16Bchunk(row,c) = c ^ ((row>>1)&3) on global source + reads.
__global__ __launch_bounds__(512, 2) void gemm256_k(const bf16* __restrict__ A,
                                                    const bf16* __restrict__ Bt,
                                                    bf16* __restrict__ C,
                                                    bf16* __restrict__ Ct) {
  __shared__ bf16 As[2][2][256][32];  // [buf][ks][row][k'] : 64 KiB
  __shared__ bf16 Bs[2][2][256][32];  // 64 KiB

  const int tid = threadIdx.x;
  const int bid = blockIdx.x;
  const int wg = (bid & 7) * 32 + (bid >> 3);  // XCD swizzle, 256 % 8 == 0 -> bijective
  const int tm = wg >> 4, tn = wg & 15;
  const int rowBase = tm * 256, colBase = tn * 256;

  const int wv = tid >> 6, lane = tid & 63;
  const int wm = wv >> 2, wn = wv & 3;
  const int t16 = lane & 15, quad = lane >> 4;
  const int wv16 = wv * 16;
  const int q8 = (quad ^ ((t16 >> 1) & 3)) * 8;  // swizzled phys chunk for ds_read
  const int wm128 = wm * 128;
  const int wn64 = wn * 64;

  // staging: thread t -> row t>>2 (128 rows/load); lane writes phys chunk t&3,
  // which holds logical chunk (t&3)^key(row), key = (row>>1)&3 = (t>>3)&3
  const int sr = tid >> 2;
  const int sc = ((tid & 3) ^ ((tid >> 3) & 3)) * 8;
  const bf16* gA = A + (size_t)(rowBase + sr) * 4096 + sc;
  const bf16* gB = Bt + (size_t)(colBase + sr) * 4096 + sc;

  f32x4 acc[8][4];
  #pragma unroll
  for (int i = 0; i < 8; ++i)
    #pragma unroll
    for (int j = 0; j < 4; ++j) acc[i][j] = (f32x4){0.f, 0.f, 0.f, 0.f};

  auto stA = [&](int buf, int s, int k0) {
    async_lds16(gA + k0 + s * 32, &As[buf][s][wv16][0]);
    async_lds16(gA + 524288 + k0 + s * 32, &As[buf][s][128 + wv16][0]);
  };
  auto stB = [&](int buf, int s, int k0) {
    async_lds16(gB + k0 + s * 32, &Bs[buf][s][wv16][0]);
    async_lds16(gB + 524288 + k0 + s * 32, &Bs[buf][s][128 + wv16][0]);
  };

  bf16x8 Ra[4], Rb[4], B0[4], B1[4];
  auto rdA = [&](bf16x8* R, int buf, int s, int g) {
    #pragma unroll
    for (int i = 0; i < 4; ++i)
      R[i] = *(const bf16x8*)&As[buf][s][wm128 + (g * 4 + i) * 16 + t16][q8];
  };
  auto rdB = [&](bf16x8* R, int buf, int s) {
    #pragma unroll
    for (int j = 0; j < 4; ++j)
      R[j] = *(const bf16x8*)&Bs[buf][s][wn64 + j * 16 + t16][q8];
  };
  auto mfma16 = [&](int g, const bf16x8* R, const bf16x8* Bv) {
    __builtin_amdgcn_s_setprio(1);
    #pragma unroll
    for (int i = 0; i < 4; ++i)
      #pragma unroll
      for (int j = 0; j < 4; ++j)
        acc[g * 4 + i][j] =
            __builtin_amdgcn_mfma_f32_16x16x32_bf16(R[i], Bv[j], acc[g * 4 + i][j], 0, 0, 0);
    __builtin_amdgcn_s_setprio(0);
  };

  // prologue: t0 -> buf0 (4 halves), t1 -> buf1 (3 halves); then "R8'" reads
  stB(0, 0, 0); stA(0, 0, 0); stB(0, 1, 0); stA(0, 1, 0);
  stB(1, 0, 64); stA(1, 0, 64); stB(1, 1, 64);
  WAIT_VM(6);  // t0 fully landed; t1's 3 halves stay in flight
  BAR();
  rdA(Ra, 0, 0, 0); rdB(B0, 0, 0);  // operands for R1's MFMA (g0,ks0,t0)

  for (int it = 0; it < 31; ++it) {
    const int kb = it * 128;
    // R1: MFMA g0ks0(t) [prev reads]; read g1ks0(t); stage t+1.Aks1
    rdA(Rb, 0, 0, 1);
    stA(1, 1, kb + 64);
    mfma16(0, Ra, B0);
    LGKM0(); BAR();
    // R2: MFMA g1ks0(t); read g0ks1(t)+Bks1(t); stage t+2.Bks0
    rdA(Ra, 0, 1, 0); rdB(B1, 0, 1);
    stB(0, 0, kb + 128);
    mfma16(1, Rb, B0);
    LGKM0(); BAR();
    // R3: MFMA g0ks1(t); read g1ks1(t); stage t+2.Aks0; vmcnt(4) -> t+1 landed
    rdA(Rb, 0, 1, 1);
    stA(0, 0, kb + 128);
    WAIT_VM(4);
    mfma16(0, Ra, B1);
    LGKM0(); BAR();
    // R4: MFMA g1ks1(t); read g0ks0(t+1)+Bks0(t+1) [buf1, fresh]; stage t+2.Bks1
    rdA(Ra, 1, 0, 0); rdB(B0, 1, 0);
    stB(0, 1, kb + 128);
    mfma16(1, Rb, B1);
    LGKM0(); BAR();
    // R5: MFMA g0ks0(t+1); read g1ks0(t+1); stage t+2.Aks1
    rdA(Rb, 1, 0, 1);
    stA(0, 1, kb + 128);
    mfma16(0, Ra, B0);
    LGKM0(); BAR();
    // R6: MFMA g1ks0(t+1); read g0ks1(t+1)+Bks1(t+1); stage t+3.Bks0
    rdA(Ra, 1, 1, 0); rdB(B1, 1, 1);
    stB(1, 0, kb + 192);
    mfma16(1, Rb, B0);
    LGKM0(); BAR();
    // R7: MFMA g0ks1(t+1); read g1ks1(t+1); stage t+3.Aks0; vmcnt(4) -> t+2 landed
    rdA(Rb, 1, 1, 1);
    stA(1, 0, kb + 192);
    WAIT_VM(4);
    mfma16(0, Ra, B1);
    LGKM0(); BAR();
    // R8: MFMA g1ks1(t+1); read g0ks0(t+2)+Bks0(t+2) [buf0, fresh]; stage t+3.Bks1
    rdA(Ra, 0, 0, 0); rdB(B0, 0, 0);
    stB(1, 1, kb + 192);
    mfma16(1, Rb, B1);
    LGKM0(); BAR();
  }

  // epilogue: tiles 62 (buf0) and 63 (buf1); only remaining stage is t63.Aks1
  rdA(Rb, 0, 0, 1);
  stA(1, 1, 4032);
  mfma16(0, Ra, B0);
  LGKM0(); BAR();
  rdA(Ra, 0, 1, 0); rdB(B1, 0, 1);
  mfma16(1, Rb, B0);
  LGKM0(); BAR();
  rdA(Rb, 0, 1, 1);
  WAIT_VM(0);  // drain: t63 fully landed (only its Aks1 was outstanding)
  mfma16(0, Ra, B1);
  LGKM0(); BAR();
  // buf1 = t63 visible to all waves; no more stages -> no more barriers
  rdA(Ra, 1, 0, 0); rdB(B0, 1, 0);
  mfma16(1, Rb, B1);
  rdA(Rb, 1, 0, 1);
  mfma16(0, Ra, B0);
  rdA(Ra, 1, 1, 0); rdB(B1, 1, 1);
  mfma16(1, Rb, B0);
  rdA(Rb, 1, 1, 1);
  mfma16(0, Ra, B1);
  mfma16(1, Rb, B1);

  // D: row = quad*4+rr (M dim), col = t16 (N dim)
  #pragma unroll
  for (int i = 0; i < 8; ++i) {
    const int row0 = rowBase + wm128 + i * 16 + quad * 4;
    #pragma unroll
    for (int j = 0; j < 4; ++j) {
      const int col = colBase + wn64 + j * 16 + t16;
      #pragma unroll
      for (int rr = 0; rr < 4; ++rr)
        C[(size_t)(row0 + rr) * 4096 + col] = (bf16)acc[i][j][rr];
    }
  }
  if (Ct) {  // transposed store: Ct[col][row], 4 contiguous bf16 (8B) per frag
    #pragma unroll
    for (int i = 0; i < 8; ++i) {
      const int row0 = rowBase + wm128 + i * 16 + quad * 4;
      #pragma unroll
      for (int j = 0; j < 4; ++j) {
        const int col = colBase + wn64 + j * 16 + t16;
        union { bf16 h[4]; uint2 u; } pk;
        #pragma unroll
        for (int rr = 0; rr < 4; ++rr) pk.h[rr] = (bf16)acc[i][j][rr];
        *(uint2*)(Ct + (size_t)col * 4096 + row0) = pk.u;
      }
    }
  }
}

// ---- mix: out[b][n][o] = sum_{kk<192} Acat[n][kk] * Wcat[o][kk] + bias[o]
//      Acat chunks: kk 0..63 from x (fp32, cvt), 64..127 from XG1, 128..191 from XG2
__global__ __launch_bounds__(256) void mix_k(const float* __restrict__ x, const bf16* __restrict__ XG1,
                                             const bf16* __restrict__ XG2, const bf16* __restrict__ Wc,
                                             const float* __restrict__ bias, float* __restrict__ out) {
  __shared__ bf16 sW[64 * 200];  // stride 200: 16B-aligned rows, 2-way-max bank aliasing (free)
  const int tid = threadIdx.x;
  const int nt = blockIdx.x, b = blockIdx.y;
  {
    // row = tid>>2 (64 rows), quarter = tid&3 covers 48 elems = 6 x bf16x8
    const int rw = tid >> 2, part = tid & 3;
    #pragma unroll
    for (int v = 0; v < 6; ++v)
      *(bf16x8*)(sW + rw * 200 + part * 48 + v * 8) = *(const bf16x8*)(Wc + rw * 192 + part * 48 + v * 8);
  }
  __syncthreads();

  const int lane = tid & 63, wv = tid >> 6;
  const int t16 = lane & 15, quad = lane >> 4;
  const int nBase = nt * 128 + wv * 32;

  f32x4 acc[2][4];
  #pragma unroll
  for (int i = 0; i < 2; ++i)
    #pragma unroll
    for (int j = 0; j < 4; ++j) acc[i][j] = (f32x4){0.f, 0.f, 0.f, 0.f};

  #pragma unroll
  for (int ch = 0; ch < 6; ++ch) {
    bf16x8 a[2];
    #pragma unroll
    for (int i = 0; i < 2; ++i) {
      const int row = nBase + i * 16 + t16;
      if (ch < 2) {
        const float* p = x + (b * 4096 + row) * 64 + ch * 32 + quad * 8;
        float4 f0 = *(const float4*)p;
        float4 f1 = *(const float4*)(p + 4);
        bf16x8 t;
        t[0] = (bf16)f0.x; t[1] = (bf16)f0.y; t[2] = (bf16)f0.z; t[3] = (bf16)f0.w;
        t[4] = (bf16)f1.x; t[5] = (bf16)f1.y; t[6] = (bf16)f1.z; t[7] = (bf16)f1.w;
        a[i] = t;
      } else {
        const bf16* src = (ch < 4) ? XG1 : XG2;
        a[i] = *(const bf16x8*)(src + row * 4096 + b * 64 + (ch & 1) * 32 + quad * 8);
      }
    }
    #pragma unroll
    for (int j = 0; j < 4; ++j) {
      bf16x8 wf = *(const bf16x8*)(sW + (j * 16 + t16) * 200 + ch * 32 + quad * 8);
      #pragma unroll
      for (int i = 0; i < 2; ++i)
        acc[i][j] = __builtin_amdgcn_mfma_f32_16x16x32_bf16(a[i], wf, acc[i][j], 0, 0, 0);
    }
  }

  #pragma unroll
  for (int j = 0; j < 4; ++j) {
    const float bb = bias[j * 16 + t16];
    #pragma unroll
    for (int i = 0; i < 2; ++i) {
      const int n0 = nBase + i * 16 + quad * 4;
      #pragma unroll
      for (int rr = 0; rr < 4; ++rr)
        out[(b * 4096 + n0 + rr) * 64 + j * 16 + t16] = acc[i][j][rr] + bb;
    }
  }
}

extern "C" void kernel_launch(void* const* d_in, const int* in_sizes, int n_in,
                              void* d_out, int out_size, void* d_ws, size_t ws_size,
                              hipStream_t stream) {
  const float* x    = (const float*)d_in[0];  // [64,4096,64]
  const float* adj  = (const float*)d_in[1];  // [4096,16]
  const float* emb  = (const float*)d_in[2];  // [16,4096]
  const float* w    = (const float*)d_in[3];  // [3,64,64]
  const float* bias = (const float*)d_in[4];  // [64]
  float* out = (float*)d_out;

  char* ws = (char*)d_ws;
  const size_t SZ = (size_t)4096 * 4096 * sizeof(bf16);  // 32 MiB
  bf16* S    = (bf16*)(ws);            // [n][m]
  bf16* XG1  = (bf16*)(ws + SZ);       // [n][bc]
  bf16* XG2  = (bf16*)(ws + 2 * SZ);   // [n][bc]
  bf16* XBUF = (bf16*)(ws + 3 * SZ);   // Xt [bc][m] (and XG1t fallback)
  const bool fused_t = ws_size >= 5 * SZ + (size_t)(64 * 192 * sizeof(bf16));
  bf16* XG1T = fused_t ? (bf16*)(ws + 4 * SZ) : XBUF;  // [bc][m]
  bf16* Wc   = (bf16*)(ws + (fused_t ? 5 : 4) * SZ);   // [64][192]

  build_wcat_k<<<48, 256, 0, stream>>>(w, Wc);
  supports_k<<<512, 256, 0, stream>>>(adj, emb, S);
  xpose_x_k<<<dim3(64, 64), 256, 0, stream>>>(x, XBUF);
  gemm256_k<<<256, 512, 0, stream>>>(S, XBUF, XG1, fused_t ? XG1T : nullptr);
  if (!fused_t) transpose_bf16_k<<<4096, 256, 0, stream>>>(XG1, XBUF);  // XG1t
  gemm256_k<<<256, 512, 0, stream>>>(S, XG1T, XG2, nullptr);            // XG2 = S @ XG1
  mix_k<<<dim3(32, 64), 256, 0, stream>>>(x, XG1, XG2, Wc, bias, out);
}

// Round 5
// 435.572 us; speedup vs baseline: 1.0552x; 1.0552x over previous
//
#include <hip/hip_runtime.h>

// AVWGCN: out[b,n,o] = sum_k sum_i xg_k[b,n,i] * w[k,i,o] + bias[o]
//   xg0 = x, xg1 = S@x, xg2 = 2*S@(S@x) - x   (S = softmax(relu(adj@emb), rows))
// Algebra: never form T2; fold "2*" and "-x" into Wcat = [w0-w2 | w1 | 2*w2].
// GEMM: round-3 schedule (best measured: 137 µs/dispatch) — 256x256, BK=64,
// 8 waves, 128 KiB LDS dbuf, chunk-XOR swizzle, single barrier per region.
// Round-4's rotation regressed (+4 µs) -> reverted; schedule is at its local
// optimum (MFMA 516 + LDS ~500 cyc/region floors vs 1289 measured; next lever
// would be structural). This round: supports_k loop-swap (emb read 1x not 8x).

typedef __bf16 bf16;
typedef __bf16 bf16x8 __attribute__((ext_vector_type(8)));
typedef float f32x4 __attribute__((ext_vector_type(4)));

__device__ __forceinline__ void async_lds16(const void* g, void* l) {
  __builtin_amdgcn_global_load_lds((const __attribute__((address_space(1))) void*)g,
                                   (__attribute__((address_space(3))) void*)l, 16, 0, 0);
}

#define FENCE() asm volatile("" ::: "memory")
#define BAR()                          \
  do {                                 \
    FENCE();                           \
    __builtin_amdgcn_s_barrier();      \
    FENCE();                           \
  } while (0)
#define WAIT_VM(n) asm volatile("s_waitcnt vmcnt(" #n ")" ::: "memory")

// ---- Wcat[o][kk] bf16, kk in [0,192): [w0-w2 | w1 | 2*w2] transposed to o-rows ----
__global__ __launch_bounds__(256) void build_wcat_k(const float* __restrict__ w, bf16* __restrict__ Wc) {
  int idx = blockIdx.x * 256 + threadIdx.x;
  if (idx >= 64 * 192) return;
  int o = idx / 192, kk = idx - o * 192;
  int k = kk >> 6, i = kk & 63;
  float v;
  if (k == 0)      v = w[i * 64 + o] - w[2 * 4096 + i * 64 + o];
  else if (k == 1) v = w[4096 + i * 64 + o];
  else             v = 2.f * w[2 * 4096 + i * 64 + o];
  Wc[idx] = (bf16)v;
}

// ---- S[n][m] = softmax(relu(adj@emb)) rows, stored bf16. 8 rows per block. ----
// Loop-swapped: emb is read ONCE per block (was 8x = 1 GB L2 traffic total);
// logits stored fp32 in 128 KB LDS; 4 barriers/block (was 32). Arithmetic order
// identical to previous version -> bit-identical S.
__global__ __launch_bounds__(256) void supports_k(const float* __restrict__ adj,
                                                  const float* __restrict__ emb,
                                                  bf16* __restrict__ S) {
  __shared__ float slog[8][4096];  // 128 KiB logit stash
  __shared__ float sadj[8][16];
  __shared__ float swred[4][8];
  const int tid = threadIdx.x;
  const int lane = tid & 63, wv = tid >> 6;
  const int n0 = blockIdx.x * 8;
  if (tid < 128) sadj[tid >> 4][tid & 15] = adj[n0 * 16 + tid];
  __syncthreads();

  float mx[8];
  #pragma unroll
  for (int r = 0; r < 8; ++r) mx[r] = 0.f;  // relu => max >= 0

  // Pass A: logits (emb read once), per-thread running max
  for (int it = 0; it < 16; ++it) {
    const int j = it * 256 + tid;
    float e[16];
    #pragma unroll
    for (int k = 0; k < 16; ++k) e[k] = emb[k * 4096 + j];
    #pragma unroll
    for (int r = 0; r < 8; ++r) {
      float v = 0.f;
      #pragma unroll
      for (int k = 0; k < 16; ++k) v = fmaf(sadj[r][k], e[k], v);
      v = fmaxf(v, 0.f);
      slog[r][j] = v;
      mx[r] = fmaxf(mx[r], v);
    }
  }
  // max reduce: wave shuffle, then cross-wave via LDS
  #pragma unroll
  for (int r = 0; r < 8; ++r) {
    #pragma unroll
    for (int off = 32; off > 0; off >>= 1) mx[r] = fmaxf(mx[r], __shfl_xor(mx[r], off, 64));
  }
  if (lane == 0) {
    #pragma unroll
    for (int r = 0; r < 8; ++r) swred[wv][r] = mx[r];
  }
  __syncthreads();
  #pragma unroll
  for (int r = 0; r < 8; ++r)
    mx[r] = fmaxf(fmaxf(swred[0][r], swred[1][r]), fmaxf(swred[2][r], swred[3][r]));

  // Pass B: exp + per-thread sum (exp values written back to slog)
  float sm[8];
  #pragma unroll
  for (int r = 0; r < 8; ++r) sm[r] = 0.f;
  for (int it = 0; it < 16; ++it) {
    const int j = it * 256 + tid;
    #pragma unroll
    for (int r = 0; r < 8; ++r) {
      float ev = __expf(slog[r][j] - mx[r]);
      slog[r][j] = ev;
      sm[r] += ev;
    }
  }
  #pragma unroll
  for (int r = 0; r < 8; ++r) {
    #pragma unroll
    for (int off = 32; off > 0; off >>= 1) sm[r] += __shfl_xor(sm[r], off, 64);
  }
  __syncthreads();  // all reads of swred (max) done before reuse
  if (lane == 0) {
    #pragma unroll
    for (int r = 0; r < 8; ++r) swred[wv][r] = sm[r];
  }
  __syncthreads();
  float inv[8];
  #pragma unroll
  for (int r = 0; r < 8; ++r)
    inv[r] = 1.f / (swred[0][r] + swred[1][r] + swred[2][r] + swred[3][r]);

  // Pass C: normalize + store bf16 (coalesced 512B per r per it)
  for (int it = 0; it < 16; ++it) {
    const int j = it * 256 + tid;
    #pragma unroll
    for (int r = 0; r < 8; ++r)
      S[(n0 + r) * 4096 + j] = (bf16)(slog[r][j] * inv[r]);
  }
}

// ---- Xt[b*64+c][m] = bf16(x[b][m][c])  (64x64 fp32 tile via LDS) ----
__global__ __launch_bounds__(256) void xpose_x_k(const float* __restrict__ x, bf16* __restrict__ Xt) {
  __shared__ float tile[64][65];
  const int tid = threadIdx.x;
  const int mt = blockIdx.x, b = blockIdx.y;
  const float* src = x + (b * 4096 + mt * 64) * 64;
  #pragma unroll
  for (int it = 0; it < 16; ++it) {
    const int idx = it * 256 + tid;
    tile[idx >> 6][idx & 63] = src[idx];  // idx = m_local*64 + c, coalesced
  }
  __syncthreads();
  #pragma unroll
  for (int it = 0; it < 16; ++it) {
    const int idx = it * 256 + tid;
    const int rr = idx >> 6, cc = idx & 63;  // rr = c (out row), cc = m_local (out col)
    Xt[(b * 64 + rr) * 4096 + mt * 64 + cc] = (bf16)tile[cc][rr];
  }
}

// ---- bf16 4096x4096 transpose: outT[j][i] = in[i][j]  (fallback if ws too small) ----
__global__ __launch_bounds__(256) void transpose_bf16_k(const bf16* __restrict__ in, bf16* __restrict__ outT) {
  __shared__ bf16 tile[64][65];
  const int tid = threadIdx.x;
  const int ti = blockIdx.x & 63, tj = blockIdx.x >> 6;
  #pragma unroll
  for (int it = 0; it < 16; ++it) {
    const int idx = it * 256 + tid;
    tile[idx >> 6][idx & 63] = in[(ti * 64 + (idx >> 6)) * 4096 + tj * 64 + (idx & 63)];
  }
  __syncthreads();
  #pragma unroll
  for (int it = 0; it < 16; ++it) {
    const int idx = it * 256 + tid;
    const int rr = idx >> 6, cc = idx & 63;
    outT[(tj * 64 + rr) * 4096 + ti * 64 + cc] = tile[cc][rr];
  }
}

// ---- C[n][bc] = A[n][:] . Bt[bc][:]  (4096^3, both operands K-contig row-major) ----
// Round-3 schedule (best measured). Regions R1..R8 over 2 K-tiles, ONE barrier
// each. Region p: { ds_read frags for region p+1 (R1/R5 also read own operands
// post-buf-switch) | stage 1 half-tile | 16 MFMA | [R4/R8: WAIT_VM(6)] | BAR }.
// Stage order per iter: R1 t+1.Aks1 | R2 t+2.Bks0 | R3 .Aks0 | R4 .Bks1 |
// R5 .Aks1 | R6 t+3.Bks0 | R7 .Aks0 | R8 .Bks1. Every stage site: old data's
// consuming MFMA is in region <= p-1. Chunk swizzle: phys16Bchunk(row,c) =
// c ^ ((row>>1)&3) on global source (LDS dst lane-linear) and ds_read offset
// (0 conflicts, round-2 PMC). Optional Ct: transposed C store (for XG1t).
__global__ __launch_bounds__(512, 2) void gemm256_k(const bf16* __restrict__ A,
                                                    const bf16* __restrict__ Bt,
                                                    bf16* __restrict__ C,
                                                    bf16* __restrict__ Ct) {
  __shared__ bf16 As[2][2][256][32];  // [buf][ks][row][k'] : 64 KiB
  __shared__ bf16 Bs[2][2][256][32];  // 64 KiB

  const int tid = threadIdx.x;
  const int bid = blockIdx.x;
  const int wg = (bid & 7) * 32 + (bid >> 3);  // XCD swizzle, 256 % 8 == 0 -> bijective
  const int tm = wg >> 4, tn = wg & 15;
  const int rowBase = tm * 256, colBase = tn * 256;

  const int wv = tid >> 6, lane = tid & 63;
  const int wm = wv >> 2, wn = wv & 3;
  const int t16 = lane & 15, quad = lane >> 4;
  const int wv16 = wv * 16;
  const int q8 = (quad ^ ((t16 >> 1) & 3)) * 8;  // swizzled phys chunk for ds_read
  const int wm128 = wm * 128;
  const int wn64 = wn * 64;

  // staging: thread t -> row t>>2 (128 rows/load); lane writes phys chunk t&3,
  // which holds logical chunk (t&3)^key(row), key = (row>>1)&3 = (t>>3)&3
  const int sr = tid >> 2;
  const int sc = ((tid & 3) ^ ((tid >> 3) & 3)) * 8;
  const bf16* gA = A + (size_t)(rowBase + sr) * 4096 + sc;
  const bf16* gB = Bt + (size_t)(colBase + sr) * 4096 + sc;

  f32x4 acc[8][4];
  #pragma unroll
  for (int i = 0; i < 8; ++i)
    #pragma unroll
    for (int j = 0; j < 4; ++j) acc[i][j] = (f32x4){0.f, 0.f, 0.f, 0.f};

  auto stA = [&](int buf, int s, int k0) {
    async_lds16(gA + k0 + s * 32, &As[buf][s][wv16][0]);
    async_lds16(gA + 524288 + k0 + s * 32, &As[buf][s][128 + wv16][0]);
  };
  auto stB = [&](int buf, int s, int k0) {
    async_lds16(gB + k0 + s * 32, &Bs[buf][s][wv16][0]);
    async_lds16(gB + 524288 + k0 + s * 32, &Bs[buf][s][128 + wv16][0]);
  };

  bf16x8 Ra[4], Rb[4], B0[4], B1[4];
  auto rdA = [&](bf16x8* R, int buf, int s, int g) {
    #pragma unroll
    for (int i = 0; i < 4; ++i)
      R[i] = *(const bf16x8*)&As[buf][s][wm128 + (g * 4 + i) * 16 + t16][q8];
  };
  auto rdB = [&](bf16x8* R, int buf, int s) {
    #pragma unroll
    for (int j = 0; j < 4; ++j)
      R[j] = *(const bf16x8*)&Bs[buf][s][wn64 + j * 16 + t16][q8];
  };
  auto mfma16 = [&](int g, const bf16x8* R, const bf16x8* Bv) {
    __builtin_amdgcn_s_setprio(1);
    #pragma unroll
    for (int i = 0; i < 4; ++i)
      #pragma unroll
      for (int j = 0; j < 4; ++j)
        acc[g * 4 + i][j] =
            __builtin_amdgcn_mfma_f32_16x16x32_bf16(R[i], Bv[j], acc[g * 4 + i][j], 0, 0, 0);
    __builtin_amdgcn_s_setprio(0);
  };

  // prologue: t0 -> buf0 (4 halves, 8 loads), t1 -> buf1 (3 halves, 6 loads)
  stB(0, 0, 0); stA(0, 0, 0); stB(0, 1, 0); stA(0, 1, 0);
  stB(1, 0, 64); stA(1, 0, 64); stB(1, 1, 64);
  WAIT_VM(6);  // t0 fully landed; t1's 3 halves stay in flight
  BAR();

  for (int it = 0; it < 31; ++it) {
    const int kb = it * 128;
    // R1: buf-switch reads (same-region consume of Ra/B0) + lookahead Rb
    rdA(Ra, 0, 0, 0); rdB(B0, 0, 0); rdA(Rb, 0, 0, 1);
    stA(1, 1, kb + 64);
    mfma16(0, Ra, B0);
    BAR();
    // R2
    rdA(Ra, 0, 1, 0); rdB(B1, 0, 1);
    stB(0, 0, kb + 128);
    mfma16(1, Rb, B0);
    BAR();
    // R3
    rdA(Rb, 0, 1, 1);
    stA(0, 0, kb + 128);
    mfma16(0, Ra, B1);
    BAR();
    // R4: counted wait -> buf1 (t_{2it+1}) fully landed after this barrier
    stB(0, 1, kb + 128);
    mfma16(1, Rb, B1);
    WAIT_VM(6);
    BAR();
    // R5: buf-switch reads of buf1 + lookahead
    rdA(Ra, 1, 0, 0); rdB(B0, 1, 0); rdA(Rb, 1, 0, 1);
    stA(0, 1, kb + 128);
    mfma16(0, Ra, B0);
    BAR();
    // R6
    rdA(Ra, 1, 1, 0); rdB(B1, 1, 1);
    stB(1, 0, kb + 192);
    mfma16(1, Rb, B0);
    BAR();
    // R7
    rdA(Rb, 1, 1, 1);
    stA(1, 0, kb + 192);
    mfma16(0, Ra, B1);
    BAR();
    // R8: counted wait -> buf0 (t_{2it+2}) fully landed after this barrier
    stB(1, 1, kb + 192);
    mfma16(1, Rb, B1);
    WAIT_VM(6);
    BAR();
  }

  // epilogue: tiles 62 (buf0) and 63 (buf1); only remaining stage is t63.Aks1
  rdA(Ra, 0, 0, 0); rdB(B0, 0, 0); rdA(Rb, 0, 0, 1);
  stA(1, 1, 4032);
  mfma16(0, Ra, B0);
  BAR();
  rdA(Ra, 0, 1, 0); rdB(B1, 0, 1);
  mfma16(1, Rb, B0);
  BAR();
  rdA(Rb, 0, 1, 1);
  mfma16(0, Ra, B1);
  BAR();
  mfma16(1, Rb, B1);
  WAIT_VM(0);  // drain: t63 fully landed
  BAR();
  rdA(Ra, 1, 0, 0); rdB(B0, 1, 0); rdA(Rb, 1, 0, 1);
  mfma16(0, Ra, B0);
  rdA(Ra, 1, 1, 0); rdB(B1, 1, 1);
  mfma16(1, Rb, B0);
  rdA(Rb, 1, 1, 1);
  mfma16(0, Ra, B1);
  mfma16(1, Rb, B1);

  // D: row = quad*4+rr (M dim), col = t16 (N dim)
  #pragma unroll
  for (int i = 0; i < 8; ++i) {
    const int row0 = rowBase + wm128 + i * 16 + quad * 4;
    #pragma unroll
    for (int j = 0; j < 4; ++j) {
      const int col = colBase + wn64 + j * 16 + t16;
      #pragma unroll
      for (int rr = 0; rr < 4; ++rr)
        C[(size_t)(row0 + rr) * 4096 + col] = (bf16)acc[i][j][rr];
    }
  }
  if (Ct) {  // transposed store: Ct[col][row], 4 contiguous bf16 (8B) per frag
    #pragma unroll
    for (int i = 0; i < 8; ++i) {
      const int row0 = rowBase + wm128 + i * 16 + quad * 4;
      #pragma unroll
      for (int j = 0; j < 4; ++j) {
        const int col = colBase + wn64 + j * 16 + t16;
        union { bf16 h[4]; uint2 u; } pk;
        #pragma unroll
        for (int rr = 0; rr < 4; ++rr) pk.h[rr] = (bf16)acc[i][j][rr];
        *(uint2*)(Ct + (size_t)col * 4096 + row0) = pk.u;
      }
    }
  }
}

// ---- mix: out[b][n][o] = sum_{kk<192} Acat[n][kk] * Wcat[o][kk] + bias[o]
//      Acat chunks: kk 0..63 from x (fp32, cvt), 64..127 from XG1, 128..191 from XG2
__global__ __launch_bounds__(256) void mix_k(const float* __restrict__ x, const bf16* __restrict__ XG1,
                                             const bf16* __restrict__ XG2, const bf16* __restrict__ Wc,
                                             const float* __restrict__ bias, float* __restrict__ out) {
  __shared__ bf16 sW[64 * 200];  // stride 200: 16B-aligned rows, 2-way-max bank aliasing (free)
  const int tid = threadIdx.x;
  const int nt = blockIdx.x, b = blockIdx.y;
  {
    // row = tid>>2 (64 rows), quarter = tid&3 covers 48 elems = 6 x bf16x8
    const int rw = tid >> 2, part = tid & 3;
    #pragma unroll
    for (int v = 0; v < 6; ++v)
      *(bf16x8*)(sW + rw * 200 + part * 48 + v * 8) = *(const bf16x8*)(Wc + rw * 192 + part * 48 + v * 8);
  }
  __syncthreads();

  const int lane = tid & 63, wv = tid >> 6;
  const int t16 = lane & 15, quad = lane >> 4;
  const int nBase = nt * 128 + wv * 32;

  f32x4 acc[2][4];
  #pragma unroll
  for (int i = 0; i < 2; ++i)
    #pragma unroll
    for (int j = 0; j < 4; ++j) acc[i][j] = (f32x4){0.f, 0.f, 0.f, 0.f};

  #pragma unroll
  for (int ch = 0; ch < 6; ++ch) {
    bf16x8 a[2];
    #pragma unroll
    for (int i = 0; i < 2; ++i) {
      const int row = nBase + i * 16 + t16;
      if (ch < 2) {
        const float* p = x + (b * 4096 + row) * 64 + ch * 32 + quad * 8;
        float4 f0 = *(const float4*)p;
        float4 f1 = *(const float4*)(p + 4);
        bf16x8 t;
        t[0] = (bf16)f0.x; t[1] = (bf16)f0.y; t[2] = (bf16)f0.z; t[3] = (bf16)f0.w;
        t[4] = (bf16)f1.x; t[5] = (bf16)f1.y; t[6] = (bf16)f1.z; t[7] = (bf16)f1.w;
        a[i] = t;
      } else {
        const bf16* src = (ch < 4) ? XG1 : XG2;
        a[i] = *(const bf16x8*)(src + row * 4096 + b * 64 + (ch & 1) * 32 + quad * 8);
      }
    }
    #pragma unroll
    for (int j = 0; j < 4; ++j) {
      bf16x8 wf = *(const bf16x8*)(sW + (j * 16 + t16) * 200 + ch * 32 + quad * 8);
      #pragma unroll
      for (int i = 0; i < 2; ++i)
        acc[i][j] = __builtin_amdgcn_mfma_f32_16x16x32_bf16(a[i], wf, acc[i][j], 0, 0, 0);
    }
  }

  #pragma unroll
  for (int j = 0; j < 4; ++j) {
    const float bb = bias[j * 16 + t16];
    #pragma unroll
    for (int i = 0; i < 2; ++i) {
      const int n0 = nBase + i * 16 + quad * 4;
      #pragma unroll
      for (int rr = 0; rr < 4; ++rr)
        out[(b * 4096 + n0 + rr) * 64 + j * 16 + t16] = acc[i][j][rr] + bb;
    }
  }
}

extern "C" void kernel_launch(void* const* d_in, const int* in_sizes, int n_in,
                              void* d_out, int out_size, void* d_ws, size_t ws_size,
                              hipStream_t stream) {
  const float* x    = (const float*)d_in[0];  // [64,4096,64]
  const float* adj  = (const float*)d_in[1];  // [4096,16]
  const float* emb  = (const float*)d_in[2];  // [16,4096]
  const float* w    = (const float*)d_in[3];  // [3,64,64]
  const float* bias = (const float*)d_in[4];  // [64]
  float* out = (float*)d_out;

  char* ws = (char*)d_ws;
  const size_t SZ = (size_t)4096 * 4096 * sizeof(bf16);  // 32 MiB
  bf16* S    = (bf16*)(ws);            // [n][m]
  bf16* XG1  = (bf16*)(ws + SZ);       // [n][bc]
  bf16* XG2  = (bf16*)(ws + 2 * SZ);   // [n][bc]
  bf16* XBUF = (bf16*)(ws + 3 * SZ);   // Xt [bc][m] (and XG1t fallback)
  const bool fused_t = ws_size >= 5 * SZ + (size_t)(64 * 192 * sizeof(bf16));
  bf16* XG1T = fused_t ? (bf16*)(ws + 4 * SZ) : XBUF;  // [bc][m]
  bf16* Wc   = (bf16*)(ws + (fused_t ? 5 : 4) * SZ);   // [64][192]

  build_wcat_k<<<48, 256, 0, stream>>>(w, Wc);
  supports_k<<<512, 256, 0, stream>>>(adj, emb, S);
  xpose_x_k<<<dim3(64, 64), 256, 0, stream>>>(x, XBUF);
  gemm256_k<<<256, 512, 0, stream>>>(S, XBUF, XG1, fused_t ? XG1T : nullptr);
  if (!fused_t) transpose_bf16_k<<<4096, 256, 0, stream>>>(XG1, XBUF);  // XG1t
  gemm256_k<<<256, 512, 0, stream>>>(S, XG1T, XG2, nullptr);            // XG2 = S @ XG1
  mix_k<<<dim3(32, 64), 256, 0, stream>>>(x, XG1, XG2, Wc, bias, out);
}

// Round 6
// 432.010 us; speedup vs baseline: 1.0639x; 1.0082x over previous
//
#include <hip/hip_runtime.h>

// AVWGCN: out[b,n,o] = sum_k sum_i xg_k[b,n,i] * w[k,i,o] + bias[o]
//   xg0 = x, xg1 = S@x, xg2 = 2*S@(S@x) - x   (S = softmax(relu(adj@emb), rows))
// Algebra: never form T2; fold "2*" and "-x" into Wcat = [w0-w2 | w1 | 2*w2].
// GEMM: round-3 schedule (best measured: ~136 µs/dispatch; round-1 2-bar and
// round-4 rotation both worse -> local optimum). This round: mix_k rewritten as
// LDS-staged mini-GEMM (x was read 16B/lane at 256B stride fp32 -> now coalesced
// staging + chunk-XOR LDS, 73KB LDS = 2 blocks/CU).

typedef __bf16 bf16;
typedef __bf16 bf16x8 __attribute__((ext_vector_type(8)));
typedef float f32x4 __attribute__((ext_vector_type(4)));

__device__ __forceinline__ void async_lds16(const void* g, void* l) {
  __builtin_amdgcn_global_load_lds((const __attribute__((address_space(1))) void*)g,
                                   (__attribute__((address_space(3))) void*)l, 16, 0, 0);
}

#define FENCE() asm volatile("" ::: "memory")
#define BAR()                          \
  do {                                 \
    FENCE();                           \
    __builtin_amdgcn_s_barrier();      \
    FENCE();                           \
  } while (0)
#define WAIT_VM(n) asm volatile("s_waitcnt vmcnt(" #n ")" ::: "memory")

// ---- Wcat[o][kk] bf16, kk in [0,192): [w0-w2 | w1 | 2*w2] transposed to o-rows ----
__global__ __launch_bounds__(256) void build_wcat_k(const float* __restrict__ w, bf16* __restrict__ Wc) {
  int idx = blockIdx.x * 256 + threadIdx.x;
  if (idx >= 64 * 192) return;
  int o = idx / 192, kk = idx - o * 192;
  int k = kk >> 6, i = kk & 63;
  float v;
  if (k == 0)      v = w[i * 64 + o] - w[2 * 4096 + i * 64 + o];
  else if (k == 1) v = w[4096 + i * 64 + o];
  else             v = 2.f * w[2 * 4096 + i * 64 + o];
  Wc[idx] = (bf16)v;
}

// ---- S[n][m] = softmax(relu(adj@emb)) rows, stored bf16. 8 rows per block. ----
// Loop-swapped: emb read once per block; logits in 128 KB LDS; 4 barriers/block.
__global__ __launch_bounds__(256) void supports_k(const float* __restrict__ adj,
                                                  const float* __restrict__ emb,
                                                  bf16* __restrict__ S) {
  __shared__ float slog[8][4096];  // 128 KiB logit stash
  __shared__ float sadj[8][16];
  __shared__ float swred[4][8];
  const int tid = threadIdx.x;
  const int lane = tid & 63, wv = tid >> 6;
  const int n0 = blockIdx.x * 8;
  if (tid < 128) sadj[tid >> 4][tid & 15] = adj[n0 * 16 + tid];
  __syncthreads();

  float mx[8];
  #pragma unroll
  for (int r = 0; r < 8; ++r) mx[r] = 0.f;  // relu => max >= 0

  for (int it = 0; it < 16; ++it) {
    const int j = it * 256 + tid;
    float e[16];
    #pragma unroll
    for (int k = 0; k < 16; ++k) e[k] = emb[k * 4096 + j];
    #pragma unroll
    for (int r = 0; r < 8; ++r) {
      float v = 0.f;
      #pragma unroll
      for (int k = 0; k < 16; ++k) v = fmaf(sadj[r][k], e[k], v);
      v = fmaxf(v, 0.f);
      slog[r][j] = v;
      mx[r] = fmaxf(mx[r], v);
    }
  }
  #pragma unroll
  for (int r = 0; r < 8; ++r) {
    #pragma unroll
    for (int off = 32; off > 0; off >>= 1) mx[r] = fmaxf(mx[r], __shfl_xor(mx[r], off, 64));
  }
  if (lane == 0) {
    #pragma unroll
    for (int r = 0; r < 8; ++r) swred[wv][r] = mx[r];
  }
  __syncthreads();
  #pragma unroll
  for (int r = 0; r < 8; ++r)
    mx[r] = fmaxf(fmaxf(swred[0][r], swred[1][r]), fmaxf(swred[2][r], swred[3][r]));

  float sm[8];
  #pragma unroll
  for (int r = 0; r < 8; ++r) sm[r] = 0.f;
  for (int it = 0; it < 16; ++it) {
    const int j = it * 256 + tid;
    #pragma unroll
    for (int r = 0; r < 8; ++r) {
      float ev = __expf(slog[r][j] - mx[r]);
      slog[r][j] = ev;
      sm[r] += ev;
    }
  }
  #pragma unroll
  for (int r = 0; r < 8; ++r) {
    #pragma unroll
    for (int off = 32; off > 0; off >>= 1) sm[r] += __shfl_xor(sm[r], off, 64);
  }
  __syncthreads();  // all reads of swred (max) done before reuse
  if (lane == 0) {
    #pragma unroll
    for (int r = 0; r < 8; ++r) swred[wv][r] = sm[r];
  }
  __syncthreads();
  float inv[8];
  #pragma unroll
  for (int r = 0; r < 8; ++r)
    inv[r] = 1.f / (swred[0][r] + swred[1][r] + swred[2][r] + swred[3][r]);

  for (int it = 0; it < 16; ++it) {
    const int j = it * 256 + tid;
    #pragma unroll
    for (int r = 0; r < 8; ++r)
      S[(n0 + r) * 4096 + j] = (bf16)(slog[r][j] * inv[r]);
  }
}

// ---- Xt[b*64+c][m] = bf16(x[b][m][c])  (64x64 fp32 tile via LDS) ----
__global__ __launch_bounds__(256) void xpose_x_k(const float* __restrict__ x, bf16* __restrict__ Xt) {
  __shared__ float tile[64][65];
  const int tid = threadIdx.x;
  const int mt = blockIdx.x, b = blockIdx.y;
  const float* src = x + (b * 4096 + mt * 64) * 64;
  #pragma unroll
  for (int it = 0; it < 16; ++it) {
    const int idx = it * 256 + tid;
    tile[idx >> 6][idx & 63] = src[idx];  // idx = m_local*64 + c, coalesced
  }
  __syncthreads();
  #pragma unroll
  for (int it = 0; it < 16; ++it) {
    const int idx = it * 256 + tid;
    const int rr = idx >> 6, cc = idx & 63;  // rr = c (out row), cc = m_local (out col)
    Xt[(b * 64 + rr) * 4096 + mt * 64 + cc] = (bf16)tile[cc][rr];
  }
}

// ---- bf16 4096x4096 transpose: outT[j][i] = in[i][j]  (fallback if ws too small) ----
__global__ __launch_bounds__(256) void transpose_bf16_k(const bf16* __restrict__ in, bf16* __restrict__ outT) {
  __shared__ bf16 tile[64][65];
  const int tid = threadIdx.x;
  const int ti = blockIdx.x & 63, tj = blockIdx.x >> 6;
  #pragma unroll
  for (int it = 0; it < 16; ++it) {
    const int idx = it * 256 + tid;
    tile[idx >> 6][idx & 63] = in[(ti * 64 + (idx >> 6)) * 4096 + tj * 64 + (idx & 63)];
  }
  __syncthreads();
  #pragma unroll
  for (int it = 0; it < 16; ++it) {
    const int idx = it * 256 + tid;
    const int rr = idx >> 6, cc = idx & 63;
    outT[(tj * 64 + rr) * 4096 + ti * 64 + cc] = tile[cc][rr];
  }
}

// ---- C[n][bc] = A[n][:] . Bt[bc][:]  (4096^3, both operands K-contig row-major) ----
// Round-3 schedule (best measured). Regions R1..R8 over 2 K-tiles, ONE barrier
// each. Chunk swizzle: phys16Bchunk(row,c) = c ^ ((row>>1)&3) on global source
// (LDS dst lane-linear) and ds_read offset (0 conflicts, round-2 PMC).
__global__ __launch_bounds__(512, 2) void gemm256_k(const bf16* __restrict__ A,
                                                    const bf16* __restrict__ Bt,
                                                    bf16* __restrict__ C,
                                                    bf16* __restrict__ Ct) {
  __shared__ bf16 As[2][2][256][32];  // [buf][ks][row][k'] : 64 KiB
  __shared__ bf16 Bs[2][2][256][32];  // 64 KiB

  const int tid = threadIdx.x;
  const int bid = blockIdx.x;
  const int wg = (bid & 7) * 32 + (bid >> 3);  // XCD swizzle, 256 % 8 == 0 -> bijective
  const int tm = wg >> 4, tn = wg & 15;
  const int rowBase = tm * 256, colBase = tn * 256;

  const int wv = tid >> 6, lane = tid & 63;
  const int wm = wv >> 2, wn = wv & 3;
  const int t16 = lane & 15, quad = lane >> 4;
  const int wv16 = wv * 16;
  const int q8 = (quad ^ ((t16 >> 1) & 3)) * 8;  // swizzled phys chunk for ds_read
  const int wm128 = wm * 128;
  const int wn64 = wn * 64;

  const int sr = tid >> 2;
  const int sc = ((tid & 3) ^ ((tid >> 3) & 3)) * 8;
  const bf16* gA = A + (size_t)(rowBase + sr) * 4096 + sc;
  const bf16* gB = Bt + (size_t)(colBase + sr) * 4096 + sc;

  f32x4 acc[8][4];
  #pragma unroll
  for (int i = 0; i < 8; ++i)
    #pragma unroll
    for (int j = 0; j < 4; ++j) acc[i][j] = (f32x4){0.f, 0.f, 0.f, 0.f};

  auto stA = [&](int buf, int s, int k0) {
    async_lds16(gA + k0 + s * 32, &As[buf][s][wv16][0]);
    async_lds16(gA + 524288 + k0 + s * 32, &As[buf][s][128 + wv16][0]);
  };
  auto stB = [&](int buf, int s, int k0) {
    async_lds16(gB + k0 + s * 32, &Bs[buf][s][wv16][0]);
    async_lds16(gB + 524288 + k0 + s * 32, &Bs[buf][s][128 + wv16][0]);
  };

  bf16x8 Ra[4], Rb[4], B0[4], B1[4];
  auto rdA = [&](bf16x8* R, int buf, int s, int g) {
    #pragma unroll
    for (int i = 0; i < 4; ++i)
      R[i] = *(const bf16x8*)&As[buf][s][wm128 + (g * 4 + i) * 16 + t16][q8];
  };
  auto rdB = [&](bf16x8* R, int buf, int s) {
    #pragma unroll
    for (int j = 0; j < 4; ++j)
      R[j] = *(const bf16x8*)&Bs[buf][s][wn64 + j * 16 + t16][q8];
  };
  auto mfma16 = [&](int g, const bf16x8* R, const bf16x8* Bv) {
    __builtin_amdgcn_s_setprio(1);
    #pragma unroll
    for (int i = 0; i < 4; ++i)
      #pragma unroll
      for (int j = 0; j < 4; ++j)
        acc[g * 4 + i][j] =
            __builtin_amdgcn_mfma_f32_16x16x32_bf16(R[i], Bv[j], acc[g * 4 + i][j], 0, 0, 0);
    __builtin_amdgcn_s_setprio(0);
  };

  // prologue: t0 -> buf0 (4 halves, 8 loads), t1 -> buf1 (3 halves, 6 loads)
  stB(0, 0, 0); stA(0, 0, 0); stB(0, 1, 0); stA(0, 1, 0);
  stB(1, 0, 64); stA(1, 0, 64); stB(1, 1, 64);
  WAIT_VM(6);  // t0 fully landed; t1's 3 halves stay in flight
  BAR();

  for (int it = 0; it < 31; ++it) {
    const int kb = it * 128;
    // R1: buf-switch reads (same-region consume of Ra/B0) + lookahead Rb
    rdA(Ra, 0, 0, 0); rdB(B0, 0, 0); rdA(Rb, 0, 0, 1);
    stA(1, 1, kb + 64);
    mfma16(0, Ra, B0);
    BAR();
    // R2
    rdA(Ra, 0, 1, 0); rdB(B1, 0, 1);
    stB(0, 0, kb + 128);
    mfma16(1, Rb, B0);
    BAR();
    // R3
    rdA(Rb, 0, 1, 1);
    stA(0, 0, kb + 128);
    mfma16(0, Ra, B1);
    BAR();
    // R4: counted wait -> buf1 (t_{2it+1}) fully landed after this barrier
    stB(0, 1, kb + 128);
    mfma16(1, Rb, B1);
    WAIT_VM(6);
    BAR();
    // R5: buf-switch reads of buf1 + lookahead
    rdA(Ra, 1, 0, 0); rdB(B0, 1, 0); rdA(Rb, 1, 0, 1);
    stA(0, 1, kb + 128);
    mfma16(0, Ra, B0);
    BAR();
    // R6
    rdA(Ra, 1, 1, 0); rdB(B1, 1, 1);
    stB(1, 0, kb + 192);
    mfma16(1, Rb, B0);
    BAR();
    // R7
    rdA(Rb, 1, 1, 1);
    stA(1, 0, kb + 192);
    mfma16(0, Ra, B1);
    BAR();
    // R8: counted wait -> buf0 (t_{2it+2}) fully landed after this barrier
    stB(1, 1, kb + 192);
    mfma16(1, Rb, B1);
    WAIT_VM(6);
    BAR();
  }

  // epilogue: tiles 62 (buf0) and 63 (buf1); only remaining stage is t63.Aks1
  rdA(Ra, 0, 0, 0); rdB(B0, 0, 0); rdA(Rb, 0, 0, 1);
  stA(1, 1, 4032);
  mfma16(0, Ra, B0);
  BAR();
  rdA(Ra, 0, 1, 0); rdB(B1, 0, 1);
  mfma16(1, Rb, B0);
  BAR();
  rdA(Rb, 0, 1, 1);
  mfma16(0, Ra, B1);
  BAR();
  mfma16(1, Rb, B1);
  WAIT_VM(0);  // drain: t63 fully landed
  BAR();
  rdA(Ra, 1, 0, 0); rdB(B0, 1, 0); rdA(Rb, 1, 0, 1);
  mfma16(0, Ra, B0);
  rdA(Ra, 1, 1, 0); rdB(B1, 1, 1);
  mfma16(1, Rb, B0);
  rdA(Rb, 1, 1, 1);
  mfma16(0, Ra, B1);
  mfma16(1, Rb, B1);

  // D: row = quad*4+rr (M dim), col = t16 (N dim)
  #pragma unroll
  for (int i = 0; i < 8; ++i) {
    const int row0 = rowBase + wm128 + i * 16 + quad * 4;
    #pragma unroll
    for (int j = 0; j < 4; ++j) {
      const int col = colBase + wn64 + j * 16 + t16;
      #pragma unroll
      for (int rr = 0; rr < 4; ++rr)
        C[(size_t)(row0 + rr) * 4096 + col] = (bf16)acc[i][j][rr];
    }
  }
  if (Ct) {  // transposed store: Ct[col][row], 4 contiguous bf16 (8B) per frag
    #pragma unroll
    for (int i = 0; i < 8; ++i) {
      const int row0 = rowBase + wm128 + i * 16 + quad * 4;
      #pragma unroll
      for (int j = 0; j < 4; ++j) {
        const int col = colBase + wn64 + j * 16 + t16;
        union { bf16 h[4]; uint2 u; } pk;
        #pragma unroll
        for (int rr = 0; rr < 4; ++rr) pk.h[rr] = (bf16)acc[i][j][rr];
        *(uint2*)(Ct + (size_t)col * 4096 + row0) = pk.u;
      }
    }
  }
}

// ---- mix: out[b][n][o] = sum_{kk<192} Acat[n][kk] * Wcat[o][kk] + bias[o]
// LDS-staged: x coalesced fp32 reads -> cvt -> swizzled ds_write; XG1/XG2 via
// global_load_lds (lane-linear dst, pre-swizzled source). Chunk-XOR key = row&7
// (128B rows, 8 chunks). 73 KB LDS -> 2 blocks/CU. One barrier.
__global__ __launch_bounds__(256) void mix_k(const float* __restrict__ x, const bf16* __restrict__ XG1,
                                             const bf16* __restrict__ XG2, const bf16* __restrict__ Wc,
                                             const float* __restrict__ bias, float* __restrict__ out) {
  __shared__ bf16 sW[64 * 200];   // stride 200 (=400B, 16B-aligned rows)
  __shared__ bf16 sX[128 * 64];   // block-local Acat chunks, swizzled
  __shared__ bf16 sG1[128 * 64];
  __shared__ bf16 sG2[128 * 64];
  const int tid = threadIdx.x;
  const int nt = blockIdx.x, b = blockIdx.y;
  const int nBase = nt * 128;
  const int lane = tid & 63, wv = tid >> 6;

  {  // Wc -> sW
    const int rw = tid >> 2, part = tid & 3;
    #pragma unroll
    for (int v = 0; v < 6; ++v)
      *(bf16x8*)(sW + rw * 200 + part * 48 + v * 8) = *(const bf16x8*)(Wc + rw * 192 + part * 48 + v * 8);
  }
  {  // XG1/XG2 -> sG1/sG2: thread t -> row (t>>3)+32p, phys chunk t&7
     // logical chunk = (t&7) ^ (row&7); dst = wv*512 + lane*8 (+p*2048): lane-linear
    const int grow = tid >> 3, gc = tid & 7;
    const int gsrc = (gc ^ (grow & 7)) * 8;
    #pragma unroll
    for (int p = 0; p < 4; ++p) {
      const int r = grow + p * 32;
      async_lds16(XG1 + (size_t)(nBase + r) * 4096 + b * 64 + gsrc, sG1 + p * 2048 + wv * 512);
      async_lds16(XG2 + (size_t)(nBase + r) * 4096 + b * 64 + gsrc, sG2 + p * 2048 + wv * 512);
    }
  }
  {  // x -> sX: thread t, pass p: row=(p*256+t)>>2, seg=t&3 (16 fp32 = 64B, coalesced)
    #pragma unroll
    for (int p = 0; p < 2; ++p) {
      const int idx = p * 256 + tid;
      const int r = idx >> 2, seg = idx & 3;
      const float* px = x + ((size_t)(b * 4096 + nBase + r)) * 64 + seg * 16;
      float4 f0 = *(const float4*)px;
      float4 f1 = *(const float4*)(px + 4);
      float4 f2 = *(const float4*)(px + 8);
      float4 f3 = *(const float4*)(px + 12);
      bf16x8 t0, t1;
      t0[0] = (bf16)f0.x; t0[1] = (bf16)f0.y; t0[2] = (bf16)f0.z; t0[3] = (bf16)f0.w;
      t0[4] = (bf16)f1.x; t0[5] = (bf16)f1.y; t0[6] = (bf16)f1.z; t0[7] = (bf16)f1.w;
      t1[0] = (bf16)f2.x; t1[1] = (bf16)f2.y; t1[2] = (bf16)f2.z; t1[3] = (bf16)f2.w;
      t1[4] = (bf16)f3.x; t1[5] = (bf16)f3.y; t1[6] = (bf16)f3.z; t1[7] = (bf16)f3.w;
      const int key = r & 7, c0 = seg * 2;
      *(bf16x8*)(sX + r * 64 + ((c0) ^ key) * 8) = t0;
      *(bf16x8*)(sX + r * 64 + ((c0 + 1) ^ key) * 8) = t1;
    }
  }
  __syncthreads();  // drains vmcnt (gload_lds) + lgkm (ds_writes)

  const int t16 = lane & 15, quad = lane >> 4;
  const int rloc = wv * 32;

  f32x4 acc[2][4];
  #pragma unroll
  for (int i = 0; i < 2; ++i)
    #pragma unroll
    for (int j = 0; j < 4; ++j) acc[i][j] = (f32x4){0.f, 0.f, 0.f, 0.f};

  #pragma unroll
  for (int ch = 0; ch < 6; ++ch) {
    const bf16* src = (ch < 2) ? sX : (ch < 4) ? sG1 : sG2;
    const int c = (ch & 1) * 4 + quad;
    bf16x8 a[2];
    #pragma unroll
    for (int i = 0; i < 2; ++i) {
      const int r = rloc + i * 16 + t16;
      a[i] = *(const bf16x8*)(src + r * 64 + ((c ^ (r & 7)) * 8));
    }
    #pragma unroll
    for (int j = 0; j < 4; ++j) {
      bf16x8 wf = *(const bf16x8*)(sW + (j * 16 + t16) * 200 + ch * 32 + quad * 8);
      #pragma unroll
      for (int i = 0; i < 2; ++i)
        acc[i][j] = __builtin_amdgcn_mfma_f32_16x16x32_bf16(a[i], wf, acc[i][j], 0, 0, 0);
    }
  }

  #pragma unroll
  for (int j = 0; j < 4; ++j) {
    const float bb = bias[j * 16 + t16];
    #pragma unroll
    for (int i = 0; i < 2; ++i) {
      const int n0 = nBase + wv * 32 + i * 16 + quad * 4;
      #pragma unroll
      for (int rr = 0; rr < 4; ++rr)
        out[(b * 4096 + n0 + rr) * 64 + j * 16 + t16] = acc[i][j][rr] + bb;
    }
  }
}

extern "C" void kernel_launch(void* const* d_in, const int* in_sizes, int n_in,
                              void* d_out, int out_size, void* d_ws, size_t ws_size,
                              hipStream_t stream) {
  const float* x    = (const float*)d_in[0];  // [64,4096,64]
  const float* adj  = (const float*)d_in[1];  // [4096,16]
  const float* emb  = (const float*)d_in[2];  // [16,4096]
  const float* w    = (const float*)d_in[3];  // [3,64,64]
  const float* bias = (const float*)d_in[4];  // [64]
  float* out = (float*)d_out;

  char* ws = (char*)d_ws;
  const size_t SZ = (size_t)4096 * 4096 * sizeof(bf16);  // 32 MiB
  bf16* S    = (bf16*)(ws);            // [n][m]
  bf16* XG1  = (bf16*)(ws + SZ);       // [n][bc]
  bf16* XG2  = (bf16*)(ws + 2 * SZ);   // [n][bc]
  bf16* XBUF = (bf16*)(ws + 3 * SZ);   // Xt [bc][m] (and XG1t fallback)
  const bool fused_t = ws_size >= 5 * SZ + (size_t)(64 * 192 * sizeof(bf16));
  bf16* XG1T = fused_t ? (bf16*)(ws + 4 * SZ) : XBUF;  // [bc][m]
  bf16* Wc   = (bf16*)(ws + (fused_t ? 5 : 4) * SZ);   // [64][192]

  build_wcat_k<<<48, 256, 0, stream>>>(w, Wc);
  supports_k<<<512, 256, 0, stream>>>(adj, emb, S);
  xpose_x_k<<<dim3(64, 64), 256, 0, stream>>>(x, XBUF);
  gemm256_k<<<256, 512, 0, stream>>>(S, XBUF, XG1, fused_t ? XG1T : nullptr);
  if (!fused_t) transpose_bf16_k<<<4096, 256, 0, stream>>>(XG1, XBUF);  // XG1t
  gemm256_k<<<256, 512, 0, stream>>>(S, XG1T, XG2, nullptr);            // XG2 = S @ XG1
  mix_k<<<dim3(32, 64), 256, 0, stream>>>(x, XG1, XG2, Wc, bias, out);
}